// Round 8
// baseline (164.444 us; speedup 1.0000x reference)
//
#include <hip/hip_runtime.h>

typedef short short8 __attribute__((ext_vector_type(8)));
typedef unsigned short ushort8 __attribute__((ext_vector_type(8)));
typedef float f32x4 __attribute__((ext_vector_type(4)));

__device__ __forceinline__ unsigned short f32_to_bf16(float f) {
  unsigned u = __float_as_uint(f);
  unsigned r = 0x7fffu + ((u >> 16) & 1u);
  return (unsigned short)((u + r) >> 16);
}
__device__ __forceinline__ float bf16_to_f32(unsigned short h) {
  return __uint_as_float(((unsigned)h) << 16);
}

// ---------------- f32 -> bf16 convert (vectorized, 8 elems/thread) ----------
__global__ void cvt_f32_bf16(const float* __restrict__ s,
                             unsigned short* __restrict__ d, int n8) {
  int i = blockIdx.x * blockDim.x + threadIdx.x;
  if (i >= n8) return;
  const float4* sp = (const float4*)s;
  float4 a = sp[2 * i], b = sp[2 * i + 1];
  ushort8 o;
  o[0] = f32_to_bf16(a.x); o[1] = f32_to_bf16(a.y);
  o[2] = f32_to_bf16(a.z); o[3] = f32_to_bf16(a.w);
  o[4] = f32_to_bf16(b.x); o[5] = f32_to_bf16(b.y);
  o[6] = f32_to_bf16(b.z); o[7] = f32_to_bf16(b.w);
  ((ushort8*)d)[i] = o;
}

// ---------------- async global->LDS (16B/lane, wave-uniform LDS base) -------
__device__ __forceinline__ void gload_lds16(const void* g, void* l) {
  auto* gp = (const __attribute__((address_space(1))) uint32_t*)((uintptr_t)g);
  auto* lp = (__attribute__((address_space(3))) uint32_t*)(uint32_t)(uintptr_t)l;
  __builtin_amdgcn_global_load_lds(gp, lp, 16, 0, 0);
}

// ---------------- 16-point DFT (radix 4x4, constant twiddles) ---------------
constexpr float C16T[16] = {
    1.f,  0.9238795325112867f,  0.7071067811865476f,  0.3826834323650898f,
    0.f, -0.3826834323650898f, -0.7071067811865476f, -0.9238795325112867f,
   -1.f, -0.9238795325112867f, -0.7071067811865476f, -0.3826834323650898f,
    0.f,  0.3826834323650898f,  0.7071067811865476f,  0.9238795325112867f};
constexpr float S16T[16] = {
    0.f,  0.3826834323650898f,  0.7071067811865476f,  0.9238795325112867f,
    1.f,  0.9238795325112867f,  0.7071067811865476f,  0.3826834323650898f,
    0.f, -0.3826834323650898f, -0.7071067811865476f, -0.9238795325112867f,
   -1.f, -0.9238795325112867f, -0.7071067811865476f, -0.3826834323650898f};

__device__ __forceinline__ void dft16(const float* xr, const float* xi,
                                      float* Xr, float* Xi, const float sgn) {
  float Tr[4][4], Ti[4][4];
#pragma unroll
  for (int c0 = 0; c0 < 4; ++c0) {
    float ar = xr[c0],      ai = xi[c0];
    float br = xr[c0 + 4],  bi = xi[c0 + 4];
    float cr = xr[c0 + 8],  ci = xi[c0 + 8];
    float dr = xr[c0 + 12], di = xi[c0 + 12];
    float Er = ar + cr, Ei = ai + ci, Fr = ar - cr, Fi = ai - ci;
    float Gr = br + dr, Gi = bi + di, Hr = br - dr, Hi = bi - di;
    Tr[c0][0] = Er + Gr; Ti[c0][0] = Ei + Gi;
    Tr[c0][2] = Er - Gr; Ti[c0][2] = Ei - Gi;
    float wHr = -sgn * Hi, wHi = sgn * Hr;
    Tr[c0][1] = Fr + wHr; Ti[c0][1] = Fi + wHi;
    Tr[c0][3] = Fr - wHr; Ti[c0][3] = Fi - wHi;
  }
#pragma unroll
  for (int u = 0; u < 16; ++u) {
    const int m = u & 3;
    float sr = Tr[0][m], si = Ti[0][m];
#pragma unroll
    for (int c0 = 1; c0 < 4; ++c0) {
      const int k = (u * c0) & 15;
      const float wr = C16T[k];
      const float wi = sgn * S16T[k];
      sr += wr * Tr[c0][m] - wi * Ti[c0][m];
      si += wr * Ti[c0][m] + wi * Tr[c0][m];
    }
    Xr[u] = sr; Xi[u] = si;
  }
}

// ---------------- fold spectral filter into encoder weights -----------------
// Writes interleaved B'' [1536][768] bf16: for output-channel c,
//   re -> row (c>>5)*64 + (c&31),  im -> row (c>>5)*64 + 32 + (c&31).
// Halves are contiguous: cols [0,384) <-> rows [0,768), cols [384,768) <->
// rows [768,1536).
__global__ __launch_bounds__(256) void fold_filter(
    const float* __restrict__ We, const float* __restrict__ be,
    const float* __restrict__ fre, const float* __restrict__ fim,
    unsigned short* __restrict__ Bpp, float* __restrict__ be_re,
    float* __restrict__ be_im) {
  __shared__ float2 S[16 * 276];
  const int tid = threadIdx.x;
  const int p = tid >> 4;
  const int q = tid & 15;
  const int item = blockIdx.x * 16 + p;
  const bool isW = item < 2304;
  const bool isB = (item >= 2304) && (item < 2307);
  const int e = isW ? (item / 3) : 0;
  const int ch = isW ? (item % 3) : (isB ? (item - 2304) : 0);
  const int sb = p * 276;

  {
    float xr[16], xi[16], Xr[16], Xi[16];
#pragma unroll
    for (int c = 0; c < 16; ++c) {
      const int crow = ch * 256 + q * 16 + c;
      xr[c] = isW ? We[(size_t)crow * 768 + e] : be[crow];
      xi[c] = 0.f;
    }
    dft16(xr, xi, Xr, Xi, -1.f);
#pragma unroll
    for (int u = 0; u < 16; ++u) S[sb + q * 17 + u] = make_float2(Xr[u], Xi[u]);
  }
  __syncthreads();

  {
    float xr[16], xi[16], Xr[16], Xi[16];
#pragma unroll
    for (int k = 0; k < 16; ++k) {
      float2 t = S[sb + k * 17 + q];
      xr[k] = t.x; xi[k] = t.y;
    }
    dft16(xr, xi, Xr, Xi, -1.f);
#pragma unroll
    for (int v = 0; v < 16; ++v) {
      float fr = fre[v * 16 + q], fi = fim[v * 16 + q];
      float tr = Xr[v] * fr - Xi[v] * fi;
      float ti = Xr[v] * fi + Xi[v] * fr;
      xr[v] = tr; xi[v] = ti;
    }
    dft16(xr, xi, Xr, Xi, 1.f);
#pragma unroll
    for (int r = 0; r < 16; ++r) S[sb + r * 17 + q] = make_float2(Xr[r], Xi[r]);
  }
  __syncthreads();

  {
    float xr[16], xi[16], Xr[16], Xi[16];
#pragma unroll
    for (int u = 0; u < 16; ++u) {
      float2 t = S[sb + q * 17 + u];
      xr[u] = t.x; xi[u] = t.y;
    }
    dft16(xr, xi, Xr, Xi, 1.f);
#pragma unroll
    for (int c = 0; c < 16; ++c) {
      const int crow = ch * 256 + q * 16 + c;
      const float rr = Xr[c] * (1.f / 256.f);
      const float ri = Xi[c] * (1.f / 256.f);
      if (isW) {
        const size_t rre = (size_t)(crow >> 5) * 64 + (crow & 31);
        Bpp[(rre)*768 + e]      = f32_to_bf16(rr);
        Bpp[(rre + 32)*768 + e] = f32_to_bf16(ri);
      } else if (isB) {
        be_re[crow] = rr;
        be_im[crow] = ri;
      }
    }
  }
}

// ---------------- encode GEMM half: R4 2-phase structure, m-major -----------
// A [M,768] bf16, B = one 768-row half of B'' (1.18 MB -> fits XCD L2 along
// with streaming A panels, matching dec's proven cache profile).
// 128x128 tile, BK=64, 4 waves, 2-phase prefetch, dbuf LDS, XOR-swizzle,
// XCD chunking. Epilogue |.| -> bf16 at column offset coff.
__global__ __launch_bounds__(256) void gemm_enc(
    const unsigned short* __restrict__ A, const unsigned short* __restrict__ B,
    const float* __restrict__ be_re, const float* __restrict__ be_im,
    unsigned short* __restrict__ out, int M, int K, int nbx, int coff) {
  __shared__ __align__(16) unsigned short As[2][128 * 64];
  __shared__ __align__(16) unsigned short Bs[2][128 * 64];

  const int tid = threadIdx.x;
  const int lane = tid & 63;
  const int wid = tid >> 6;
  const int wr = wid >> 1, wc = wid & 1;

  const int nwg = gridDim.x;
  const int cpx = nwg >> 3;
  const int bid = blockIdx.x;
  const int lid = (bid & 7) * cpx + (bid >> 3);
  const int m0 = (lid / nbx) * 128, n0 = (lid % nbx) * 128;

  const int lr8 = lane >> 3;
  const int swk = ((lane & 7) ^ lr8) * 8;

  f32x4 acc[4][4] = {};

  auto STAGE = [&](int buf, int k0) {
#pragma unroll
    for (int c = 0; c < 4; ++c) {
      const int rowc = wid * 32 + c * 8;
      gload_lds16(A + (size_t)(m0 + rowc + lr8) * K + (k0 + swk),
                  &As[buf][rowc * 64]);
      gload_lds16(B + (size_t)(n0 + rowc + lr8) * K + (k0 + swk),
                  &Bs[buf][rowc * 64]);
    }
  };

  const int rsel = lane & 15;
  auto COMPUTE = [&](int buf) {
#pragma unroll
    for (int ks = 0; ks < 2; ++ks) {
      const int kbyte = ks * 64 + (lane >> 4) * 16;
      short8 af[4], bf[4];
#pragma unroll
      for (int m = 0; m < 4; ++m) {
        const int row = wr * 64 + m * 16 + rsel;
        af[m] = *(const short8*)((const char*)&As[buf][0] +
                                 row * 128 + (kbyte ^ ((row & 7) << 4)));
      }
#pragma unroll
      for (int n = 0; n < 4; ++n) {
        const int row = wc * 64 + n * 16 + rsel;
        bf[n] = *(const short8*)((const char*)&Bs[buf][0] +
                                 row * 128 + (kbyte ^ ((row & 7) << 4)));
      }
#pragma unroll
      for (int m = 0; m < 4; ++m)
#pragma unroll
        for (int n = 0; n < 4; ++n)
          acc[m][n] = __builtin_amdgcn_mfma_f32_16x16x32_bf16(
              af[m], bf[n], acc[m][n], 0, 0, 0);
    }
  };

  const int nk = K >> 6;
  STAGE(0, 0);
  __syncthreads();
  int cur = 0;
  for (int t = 1; t < nk; ++t) {
    STAGE(cur ^ 1, t * 64);
    COMPUTE(cur);
    __syncthreads();
    cur ^= 1;
  }
  COMPUTE(cur);

  // acc[m][n] (n=0,1) = re, acc[m][n+2] = im of the same output column.
  const int fr = lane & 15, fq = lane >> 4;
  const int cbase = coff + ((n0 + wc * 64) >> 1);  // 64 B''-rows -> 32 cols
#pragma unroll
  for (int n = 0; n < 2; ++n) {
    const int gcol = cbase + n * 16 + fr;
    const float br = be_re[gcol], bi = be_im[gcol];
#pragma unroll
    for (int m = 0; m < 4; ++m) {
      const int grow = m0 + wr * 64 + m * 16 + fq * 4;
#pragma unroll
      for (int j = 0; j < 4; ++j) {
        const float re = acc[m][n][j] + br;
        const float im = acc[m][n + 2][j] + bi;
        out[(size_t)(grow + j) * 768 + gcol] =
            f32_to_bf16(sqrtf(re * re + im * im));
      }
    }
  }
}

// ---------------- decode GEMM: C = A * B^T + bias, f32 out (m-major) --------
__global__ __launch_bounds__(256) void gemm_bt(
    const unsigned short* __restrict__ A, const unsigned short* __restrict__ B,
    const float* __restrict__ bias, float* __restrict__ out,
    int M, int N, int K, int nbx) {
  __shared__ __align__(16) unsigned short As[2][128 * 64];
  __shared__ __align__(16) unsigned short Bs[2][128 * 64];

  const int tid = threadIdx.x;
  const int lane = tid & 63;
  const int wid = tid >> 6;
  const int wr = wid >> 1, wc = wid & 1;

  const int nwg = gridDim.x;
  const int cpx = nwg >> 3;
  const int bid = blockIdx.x;
  const int lid = (bid & 7) * cpx + (bid >> 3);
  const int m0 = (lid / nbx) * 128, n0 = (lid % nbx) * 128;

  const int lr8 = lane >> 3;
  const int swk = ((lane & 7) ^ lr8) * 8;

  f32x4 acc[4][4] = {};

  auto STAGE = [&](int buf, int k0) {
#pragma unroll
    for (int c = 0; c < 4; ++c) {
      const int rowc = wid * 32 + c * 8;
      gload_lds16(A + (size_t)(m0 + rowc + lr8) * K + (k0 + swk),
                  &As[buf][rowc * 64]);
      gload_lds16(B + (size_t)(n0 + rowc + lr8) * K + (k0 + swk),
                  &Bs[buf][rowc * 64]);
    }
  };

  const int rsel = lane & 15;
  auto COMPUTE = [&](int buf) {
#pragma unroll
    for (int ks = 0; ks < 2; ++ks) {
      const int kbyte = ks * 64 + (lane >> 4) * 16;
      short8 af[4], bf[4];
#pragma unroll
      for (int m = 0; m < 4; ++m) {
        const int row = wr * 64 + m * 16 + rsel;
        af[m] = *(const short8*)((const char*)&As[buf][0] +
                                 row * 128 + (kbyte ^ ((row & 7) << 4)));
      }
#pragma unroll
      for (int n = 0; n < 4; ++n) {
        const int row = wc * 64 + n * 16 + rsel;
        bf[n] = *(const short8*)((const char*)&Bs[buf][0] +
                                 row * 128 + (kbyte ^ ((row & 7) << 4)));
      }
#pragma unroll
      for (int m = 0; m < 4; ++m)
#pragma unroll
        for (int n = 0; n < 4; ++n)
          acc[m][n] = __builtin_amdgcn_mfma_f32_16x16x32_bf16(
              af[m], bf[n], acc[m][n], 0, 0, 0);
    }
  };

  const int nk = K >> 6;
  STAGE(0, 0);
  __syncthreads();
  int cur = 0;
  for (int t = 1; t < nk; ++t) {
    STAGE(cur ^ 1, t * 64);
    COMPUTE(cur);
    __syncthreads();
    cur ^= 1;
  }
  COMPUTE(cur);

  const int fr = lane & 15, fq = lane >> 4;
#pragma unroll
  for (int n = 0; n < 4; ++n) {
    const int gcol = n0 + wc * 64 + n * 16 + fr;
    const float bv = bias[gcol];
#pragma unroll
    for (int m = 0; m < 4; ++m) {
      const int grow = m0 + wr * 64 + m * 16 + fq * 4;
#pragma unroll
      for (int j = 0; j < 4; ++j)
        out[(size_t)(grow + j) * N + gcol] = acc[m][n][j] + bv;
    }
  }
}

// ---------------- launcher ---------------------------------------------------
extern "C" void kernel_launch(void* const* d_in, const int* in_sizes, int n_in,
                              void* d_out, int out_size, void* d_ws,
                              size_t ws_size, hipStream_t stream) {
  const float* x   = (const float*)d_in[0];
  const float* We  = (const float*)d_in[1];
  const float* be  = (const float*)d_in[2];
  const float* fre = (const float*)d_in[3];
  const float* fim = (const float*)d_in[4];
  const float* Wd  = (const float*)d_in[5];
  const float* bd  = (const float*)d_in[6];

  const int E = 768, C = 768;
  const int nX = in_sizes[0];                  // 19,267,584
  const int M  = nX / E;                       // 25088
  const int nW = E * C;                        // 589,824

  char* w = (char*)d_ws;
  unsigned short* xb    = (unsigned short*)w;                    // nX bf16
  unsigned short* Wdb   = (unsigned short*)(w + (size_t)nX * 2); // nW bf16
  unsigned short* Bpp   = Wdb + nW;                              // 2*nW bf16
  float*          be_re = (float*)(Bpp + 2 * (size_t)nW);
  float*          be_im = be_re + C;
  unsigned short* hb    = (unsigned short*)(be_im + C);          // nX bf16

  cvt_f32_bf16<<<(nX / 8 + 255) / 256, 256, 0, stream>>>(x, xb, nX / 8);
  cvt_f32_bf16<<<(nW / 8 + 255) / 256, 256, 0, stream>>>(Wd, Wdb, nW / 8);

  // fold ifft2(fft2(.)*filt)/256 into interleaved complex encoder weights
  fold_filter<<<145, 256, 0, stream>>>(We, be, fre, fim, Bpp, be_re, be_im);

  // a = |x @ We'^T + be'|  (bf16, in ws); TWO half-launches, each with a
  // 1.18 MB B half (dec's proven L2 profile). grid 1176 = 196*6, m-major.
  const int nbx1 = 6;
  gemm_enc<<<nbx1 * (M / 128), 256, 0, stream>>>(xb, Bpp, be_re, be_im, hb, M,
                                                 E, nbx1, 0);
  gemm_enc<<<nbx1 * (M / 128), 256, 0, stream>>>(xb, Bpp + (size_t)768 * 768,
                                                 be_re, be_im, hb, M, E, nbx1,
                                                 384);

  // out = a @ Wd^T + bd  (f32); grid 1176 = 196*6, m-major
  const int nbx2 = E / 128;
  gemm_bt<<<nbx2 * (M / 128), 256, 0, stream>>>(hb, Wdb, bd, (float*)d_out, M,
                                                E, C, nbx2);
}

// Round 9
// 153.657 us; speedup vs baseline: 1.0702x; 1.0702x over previous
//
#include <hip/hip_runtime.h>

typedef short short8 __attribute__((ext_vector_type(8)));
typedef unsigned short ushort8 __attribute__((ext_vector_type(8)));
typedef float f32x4 __attribute__((ext_vector_type(4)));

__device__ __forceinline__ unsigned short f32_to_bf16(float f) {
  unsigned u = __float_as_uint(f);
  unsigned r = 0x7fffu + ((u >> 16) & 1u);
  return (unsigned short)((u + r) >> 16);
}

// ---------------- f32 -> bf16 convert (vectorized, 8 elems/thread) ----------
__global__ void cvt_f32_bf16(const float* __restrict__ s,
                             unsigned short* __restrict__ d, int n8) {
  int i = blockIdx.x * blockDim.x + threadIdx.x;
  if (i >= n8) return;
  const float4* sp = (const float4*)s;
  float4 a = sp[2 * i], b = sp[2 * i + 1];
  ushort8 o;
  o[0] = f32_to_bf16(a.x); o[1] = f32_to_bf16(a.y);
  o[2] = f32_to_bf16(a.z); o[3] = f32_to_bf16(a.w);
  o[4] = f32_to_bf16(b.x); o[5] = f32_to_bf16(b.y);
  o[6] = f32_to_bf16(b.z); o[7] = f32_to_bf16(b.w);
  ((ushort8*)d)[i] = o;
}

// ---------------- async global->LDS (16B/lane, wave-uniform LDS base) -------
__device__ __forceinline__ void gload_lds16(const void* g, void* l) {
  auto* gp = (const __attribute__((address_space(1))) uint32_t*)((uintptr_t)g);
  auto* lp = (__attribute__((address_space(3))) uint32_t*)(uint32_t)(uintptr_t)l;
  __builtin_amdgcn_global_load_lds(gp, lp, 16, 0, 0);
}

// ---------------- twiddle tables: e^{2*pi*i*k/16} ----------------------------
constexpr float C16T[16] = {
    1.f,  0.9238795325112867f,  0.7071067811865476f,  0.3826834323650898f,
    0.f, -0.3826834323650898f, -0.7071067811865476f, -0.9238795325112867f,
   -1.f, -0.9238795325112867f, -0.7071067811865476f, -0.3826834323650898f,
    0.f,  0.3826834323650898f,  0.7071067811865476f,  0.9238795325112867f};
constexpr float S16T[16] = {
    0.f,  0.3826834323650898f,  0.7071067811865476f,  0.9238795325112867f,
    1.f,  0.9238795325112867f,  0.7071067811865476f,  0.3826834323650898f,
    0.f, -0.3826834323650898f, -0.7071067811865476f, -0.9238795325112867f,
   -1.f, -0.9238795325112867f, -0.7071067811865476f, -0.3826834323650898f};

// ---------------- build circulant spectral operator --------------------------
// ifft2(fft2(h)*F) == circular-conv(h, G), G = ifft2(F) (16x16 complex).
// Gpp [512][256] bf16: for out-pixel p, row (p>>5)*64+(p&31) = re,
// row +32 = im; Gpp[row][q] = G[(p1-q1)&15][(p2-q2)&15].
// Grid 256 blocks: every block computes G (redundant, tiny), block p writes
// its two 512B rows coalesced (thread q -> consecutive bf16).
__global__ __launch_bounds__(256) void build_gpp(
    const float* __restrict__ fre, const float* __restrict__ fim,
    unsigned short* __restrict__ Gpp) {
  __shared__ float Gr[256], Gi[256];
  const int t = threadIdx.x;
  const int d1 = t >> 4, d2 = t & 15;
  float sr = 0.f, si = 0.f;
#pragma unroll
  for (int v1 = 0; v1 < 16; ++v1) {
    const int k1 = (v1 * d1) & 15;
#pragma unroll
    for (int v2 = 0; v2 < 16; ++v2) {
      const int k = (k1 + v2 * d2) & 15;
      const float c = C16T[k], s = S16T[k];
      const float a = fre[v1 * 16 + v2], b = fim[v1 * 16 + v2];
      sr += a * c - b * s;
      si += a * s + b * c;
    }
  }
  Gr[t] = sr * (1.f / 256.f);
  Gi[t] = si * (1.f / 256.f);
  __syncthreads();
  const int p = blockIdx.x;
  const int p1 = p >> 4, p2 = p & 15;
  const size_t rre = (size_t)(p >> 5) * 64 + (p & 31);
  const int q1 = t >> 4, q2 = t & 15;
  const int idx = (((p1 - q1) & 15) << 4) | ((p2 - q2) & 15);
  Gpp[rre * 256 + t] = f32_to_bf16(Gr[idx]);
  Gpp[(rre + 32) * 256 + t] = f32_to_bf16(Gi[idx]);
}

// ---------------- GEMM: C = A * B^T + bias (2-phase, dbuf, swizzle, XCD) ----
// A [M,K] bf16 row-major, B [N,K] bf16 row-major. 128x128 tile, BK=64,
// 4 waves, 2-phase prefetch, dbuf LDS, XOR-swizzle, XCD chunking, m-major.
// OUT_BF16=1 -> bf16 out, else f32. Proven ~920 TF at this shape (dec).
template <int OUT_BF16>
__global__ __launch_bounds__(256) void gemm_bt(
    const unsigned short* __restrict__ A, const unsigned short* __restrict__ B,
    const float* __restrict__ bias, void* __restrict__ out,
    int M, int N, int K, int nbx) {
  __shared__ __align__(16) unsigned short As[2][128 * 64];
  __shared__ __align__(16) unsigned short Bs[2][128 * 64];

  const int tid = threadIdx.x;
  const int lane = tid & 63;
  const int wid = tid >> 6;
  const int wr = wid >> 1, wc = wid & 1;

  const int nwg = gridDim.x;
  const int cpx = nwg >> 3;
  const int bid = blockIdx.x;
  const int lid = (bid & 7) * cpx + (bid >> 3);
  const int m0 = (lid / nbx) * 128, n0 = (lid % nbx) * 128;

  const int lr8 = lane >> 3;
  const int swk = ((lane & 7) ^ lr8) * 8;

  f32x4 acc[4][4] = {};

  auto STAGE = [&](int buf, int k0) {
#pragma unroll
    for (int c = 0; c < 4; ++c) {
      const int rowc = wid * 32 + c * 8;
      gload_lds16(A + (size_t)(m0 + rowc + lr8) * K + (k0 + swk),
                  &As[buf][rowc * 64]);
      gload_lds16(B + (size_t)(n0 + rowc + lr8) * K + (k0 + swk),
                  &Bs[buf][rowc * 64]);
    }
  };

  const int rsel = lane & 15;
  auto COMPUTE = [&](int buf) {
#pragma unroll
    for (int ks = 0; ks < 2; ++ks) {
      const int kbyte = ks * 64 + (lane >> 4) * 16;
      short8 af[4], bf[4];
#pragma unroll
      for (int m = 0; m < 4; ++m) {
        const int row = wr * 64 + m * 16 + rsel;
        af[m] = *(const short8*)((const char*)&As[buf][0] +
                                 row * 128 + (kbyte ^ ((row & 7) << 4)));
      }
#pragma unroll
      for (int n = 0; n < 4; ++n) {
        const int row = wc * 64 + n * 16 + rsel;
        bf[n] = *(const short8*)((const char*)&Bs[buf][0] +
                                 row * 128 + (kbyte ^ ((row & 7) << 4)));
      }
#pragma unroll
      for (int m = 0; m < 4; ++m)
#pragma unroll
        for (int n = 0; n < 4; ++n)
          acc[m][n] = __builtin_amdgcn_mfma_f32_16x16x32_bf16(
              af[m], bf[n], acc[m][n], 0, 0, 0);
    }
  };

  const int nk = K >> 6;
  STAGE(0, 0);
  __syncthreads();
  int cur = 0;
  for (int t = 1; t < nk; ++t) {
    STAGE(cur ^ 1, t * 64);
    COMPUTE(cur);
    __syncthreads();
    cur ^= 1;
  }
  COMPUTE(cur);

  const int fr = lane & 15, fq = lane >> 4;
#pragma unroll
  for (int n = 0; n < 4; ++n) {
    const int gcol = n0 + wc * 64 + n * 16 + fr;
    const float bv = bias[gcol];
#pragma unroll
    for (int m = 0; m < 4; ++m) {
      const int grow = m0 + wr * 64 + m * 16 + fq * 4;
#pragma unroll
      for (int j = 0; j < 4; ++j) {
        const float v = acc[m][n][j] + bv;
        if (OUT_BF16)
          ((unsigned short*)out)[(size_t)(grow + j) * N + gcol] = f32_to_bf16(v);
        else
          ((float*)out)[(size_t)(grow + j) * N + gcol] = v;
      }
    }
  }
}

// ---------------- spectral GEMM: a = |h2 @ Gpp^T|, bf16 out ------------------
// A = h reinterpreted [M2=75264, 256] (patch-channel rows), B = Gpp [512,256]
// interleaved re/im (32-col groups). K=256 (4 BK-tiles). Same 2-phase body.
// Epilogue: acc[m][n]/acc[m][n+2] = re/im of pixel cbase+n*16+fr;
// out[row*256 + pix] = bf16(sqrt(re^2+im^2)). No bias (be folded into h).
__global__ __launch_bounds__(256) void gemm_spec(
    const unsigned short* __restrict__ A, const unsigned short* __restrict__ B,
    unsigned short* __restrict__ out, int M2, int nbx) {
  __shared__ __align__(16) unsigned short As[2][128 * 64];
  __shared__ __align__(16) unsigned short Bs[2][128 * 64];

  const int K = 256;
  const int tid = threadIdx.x;
  const int lane = tid & 63;
  const int wid = tid >> 6;
  const int wr = wid >> 1, wc = wid & 1;

  const int nwg = gridDim.x;
  const int cpx = nwg >> 3;
  const int bid = blockIdx.x;
  const int lid = (bid & 7) * cpx + (bid >> 3);
  const int m0 = (lid / nbx) * 128, n0 = (lid % nbx) * 128;

  const int lr8 = lane >> 3;
  const int swk = ((lane & 7) ^ lr8) * 8;

  f32x4 acc[4][4] = {};

  auto STAGE = [&](int buf, int k0) {
#pragma unroll
    for (int c = 0; c < 4; ++c) {
      const int rowc = wid * 32 + c * 8;
      gload_lds16(A + (size_t)(m0 + rowc + lr8) * K + (k0 + swk),
                  &As[buf][rowc * 64]);
      gload_lds16(B + (size_t)(n0 + rowc + lr8) * K + (k0 + swk),
                  &Bs[buf][rowc * 64]);
    }
  };

  const int rsel = lane & 15;
  auto COMPUTE = [&](int buf) {
#pragma unroll
    for (int ks = 0; ks < 2; ++ks) {
      const int kbyte = ks * 64 + (lane >> 4) * 16;
      short8 af[4], bf[4];
#pragma unroll
      for (int m = 0; m < 4; ++m) {
        const int row = wr * 64 + m * 16 + rsel;
        af[m] = *(const short8*)((const char*)&As[buf][0] +
                                 row * 128 + (kbyte ^ ((row & 7) << 4)));
      }
#pragma unroll
      for (int n = 0; n < 4; ++n) {
        const int row = wc * 64 + n * 16 + rsel;
        bf[n] = *(const short8*)((const char*)&Bs[buf][0] +
                                 row * 128 + (kbyte ^ ((row & 7) << 4)));
      }
#pragma unroll
      for (int m = 0; m < 4; ++m)
#pragma unroll
        for (int n = 0; n < 4; ++n)
          acc[m][n] = __builtin_amdgcn_mfma_f32_16x16x32_bf16(
              af[m], bf[n], acc[m][n], 0, 0, 0);
    }
  };

  const int nk = K >> 6;  // 4
  STAGE(0, 0);
  __syncthreads();
  int cur = 0;
  for (int t = 1; t < nk; ++t) {
    STAGE(cur ^ 1, t * 64);
    COMPUTE(cur);
    __syncthreads();
    cur ^= 1;
  }
  COMPUTE(cur);

  // acc[m][n] (n=0,1) = re, acc[m][n+2] = im of pixel cbase + n*16 + fr
  const int fr = lane & 15, fq = lane >> 4;
  const int cbase = (n0 + wc * 64) >> 1;
#pragma unroll
  for (int n = 0; n < 2; ++n) {
    const int gcol = cbase + n * 16 + fr;
#pragma unroll
    for (int m = 0; m < 4; ++m) {
      const int grow = m0 + wr * 64 + m * 16 + fq * 4;
#pragma unroll
      for (int j = 0; j < 4; ++j) {
        const float re = acc[m][n][j];
        const float im = acc[m][n + 2][j];
        out[(size_t)(grow + j) * 256 + gcol] =
            f32_to_bf16(sqrtf(re * re + im * im));
      }
    }
  }
}

// ---------------- launcher ---------------------------------------------------
extern "C" void kernel_launch(void* const* d_in, const int* in_sizes, int n_in,
                              void* d_out, int out_size, void* d_ws,
                              size_t ws_size, hipStream_t stream) {
  const float* x   = (const float*)d_in[0];
  const float* We  = (const float*)d_in[1];
  const float* be  = (const float*)d_in[2];
  const float* fre = (const float*)d_in[3];
  const float* fim = (const float*)d_in[4];
  const float* Wd  = (const float*)d_in[5];
  const float* bd  = (const float*)d_in[6];

  const int E = 768, C = 768;
  const int nX = in_sizes[0];                  // 19,267,584
  const int M  = nX / E;                       // 25088
  const int nW = E * C;                        // 589,824

  char* w = (char*)d_ws;
  unsigned short* xb  = (unsigned short*)w;                      // nX bf16 (reused as ab)
  unsigned short* Web = (unsigned short*)(w + (size_t)nX * 2);   // nW bf16
  unsigned short* Wdb = Web + nW;                                // nW bf16
  unsigned short* Gpp = Wdb + nW;                                // 512*256 bf16
  unsigned short* hb  = Gpp + 512 * 256;                         // nX bf16

  cvt_f32_bf16<<<(nX / 8 + 255) / 256, 256, 0, stream>>>(x, xb, nX / 8);
  cvt_f32_bf16<<<(nW / 8 + 255) / 256, 256, 0, stream>>>(We, Web, nW / 8);
  cvt_f32_bf16<<<(nW / 8 + 255) / 256, 256, 0, stream>>>(Wd, Wdb, nW / 8);

  // circulant spectral operator G = ifft2(filter), interleaved re/im rows
  build_gpp<<<256, 256, 0, stream>>>(fre, fim, Gpp);

  // h = x @ We^T + be  (bf16); grid 1176 = 196*6, m-major
  gemm_bt<1><<<6 * (M / 128), 256, 0, stream>>>(xb, Web, be, hb, M, C, E, 6);

  // a = |h (.) G|  : [75264,256] @ Gpp[512,256]^T, |.| epilogue -> ab (= xb)
  const int M2 = M * 3;                        // 75264
  gemm_spec<<<4 * (M2 / 128), 256, 0, stream>>>(hb, Gpp, xb, M2, 4);

  // out = a @ Wd^T + bd  (f32); grid 1176 = 196*6, m-major
  gemm_bt<0><<<6 * (M / 128), 256, 0, stream>>>(xb, Wdb, bd, (float*)d_out, M,
                                                E, C, 6);
}